// Round 11
// baseline (166.724 us; speedup 1.0000x reference)
//
#include <hip/hip_runtime.h>

#define WIN 33
#define WIDTH 128
#define MPTS 64
#define NN 2048
#define MM 2048
#define DD 64
#define NQ 2080   // N + 2L

typedef __bf16 bf16x8 __attribute__((ext_vector_type(8)));
typedef float f32x4 __attribute__((ext_vector_type(4)));

__device__ __forceinline__ unsigned short f2bf(float x) {
  union { float f; unsigned int u; } v; v.f = x;
  unsigned int r = v.u + 0x7FFFu + ((v.u >> 16) & 1u);  // RNE
  return (unsigned short)(r >> 16);
}
__device__ __forceinline__ float sigf(float x) { return 1.0f / (1.0f + __expf(-x)); }

// async global->LDS, 16B per lane, fire-and-forget (tracked by vmcnt)
__device__ __forceinline__ void gll16(const unsigned short* g, unsigned short* l) {
  __builtin_amdgcn_global_load_lds(
      (const __attribute__((address_space(1))) unsigned int*)g,
      (__attribute__((address_space(3))) unsigned int*)l, 16, 0, 0);
}

__device__ __forceinline__ bf16x8 cvt8(const float4& a, const float4& b) {
  union { bf16x8 v; unsigned short s[8]; } u;
  u.s[0] = f2bf(a.x); u.s[1] = f2bf(a.y); u.s[2] = f2bf(a.z); u.s[3] = f2bf(a.w);
  u.s[4] = f2bf(b.x); u.s[5] = f2bf(b.y); u.s[6] = f2bf(b.z); u.s[7] = f2bf(b.w);
  return u.v;
}

// ------------- fused prep: MLP (bid<33) + transpose (bid>=33) + out-zero ---
// R9 structure: MLP = 4 phases / 3 barriers, weights direct global->regs.
__global__ __launch_bounds__(256) void k_prep(const float* __restrict__ xi,
                                              unsigned short* __restrict__ xiT,
                                              const float* __restrict__ u,
                                              const float* __restrict__ w0,
                                              const float* __restrict__ b0,
                                              const float* __restrict__ w,
                                              const float* __restrict__ bias,
                                              unsigned short* __restrict__ u1bf,
                                              float* __restrict__ out) {
  extern __shared__ char smem[];
  int bid = blockIdx.x;
  int tid = threadIdx.x;

  if (bid < 33) {
    constexpr int AS = 136;
    float* biass = (float*)smem;                              // 1,536 B
    unsigned short* actA = (unsigned short*)(smem + 1536);    // 17,408 B
    unsigned short* actB = (unsigned short*)(smem + 18944);   // 17,408 B
    int j = bid;
    int wv = tid >> 6, lane = tid & 63, l15 = lane & 15, l4 = lane >> 4;
    int colb = l4 << 3;

    const float* wb0 = w + (size_t)j * 16384;
    const float* wb1 = w + (size_t)(WIN + j) * 16384;

    float4 wr0[8], wr1[16], wr2[16];

    {
      float4 ureg[4];
#pragma unroll
      for (int r = 0; r < 4; ++r) {
        int c = tid + (r << 8);
        ureg[r] = *(const float4*)&u[(size_t)(c >> 4) * DD + ((c & 15) << 2)];
      }
#pragma unroll
      for (int s = 0; s < 2; ++s)
#pragma unroll
        for (int t = 0; t < 2; ++t) {
          int row = wv * 32 + s * 16 + l15, col = (t << 5) + colb;
          const float* p = &w0[((size_t)j * 128 + row) * 64 + col];
          wr0[(s * 2 + t) * 2 + 0] = *(const float4*)p;
          wr0[(s * 2 + t) * 2 + 1] = *(const float4*)(p + 4);
        }
#pragma unroll
      for (int s = 0; s < 2; ++s)
#pragma unroll
        for (int t = 0; t < 4; ++t) {
          int row = wv * 32 + s * 16 + l15, col = (t << 5) + colb;
          const float* p = &wb0[(size_t)row * 128 + col];
          wr1[(s * 4 + t) * 2 + 0] = *(const float4*)p;
          wr1[(s * 4 + t) * 2 + 1] = *(const float4*)(p + 4);
        }
      if (tid < 128) {
        biass[tid]       = b0[j * 128 + tid];
        biass[128 + tid] = bias[(size_t)j * 128 + tid];
        biass[256 + tid] = bias[(size_t)(WIN + j) * 128 + tid];
      }
#pragma unroll
      for (int r = 0; r < 4; ++r) {
        int c = tid + (r << 8);
        float4 v = ureg[r];
        ushort4 h; h.x = f2bf(v.x); h.y = f2bf(v.y); h.z = f2bf(v.z); h.w = f2bf(v.w);
        *(ushort4*)&actA[(c >> 4) * AS + ((c & 15) << 2)] = h;
      }
    }
    __syncthreads();

#pragma unroll
    for (int s = 0; s < 2; ++s)
#pragma unroll
      for (int t = 0; t < 4; ++t) {
        int row = wv * 32 + s * 16 + l15, col = (t << 5) + colb;
        const float* p = &wb1[(size_t)row * 128 + col];
        wr2[(s * 4 + t) * 2 + 0] = *(const float4*)p;
        wr2[(s * 4 + t) * 2 + 1] = *(const float4*)(p + 4);
      }
    {
      f32x4 acc[2][4] = {};
#pragma unroll
      for (int t = 0; t < 2; ++t) {
        int col = (t << 5) + colb;
        bf16x8 a[2], b[4];
#pragma unroll
        for (int s = 0; s < 2; ++s)
          a[s] = cvt8(wr0[(s * 2 + t) * 2], wr0[(s * 2 + t) * 2 + 1]);
#pragma unroll
        for (int q = 0; q < 4; ++q)
          b[q] = *(const bf16x8*)&actA[(q * 16 + l15) * AS + col];
#pragma unroll
        for (int s = 0; s < 2; ++s)
#pragma unroll
          for (int q = 0; q < 4; ++q)
            acc[s][q] = __builtin_amdgcn_mfma_f32_16x16x32_bf16(a[s], b[q], acc[s][q], 0, 0, 0);
      }
#pragma unroll
      for (int s = 0; s < 2; ++s)
#pragma unroll
        for (int q = 0; q < 4; ++q) {
          int p = q * 16 + l15;
          int k0 = wv * 32 + s * 16 + (l4 << 2);
          ushort4 st;
          st.x = f2bf(sigf(acc[s][q][0] + biass[k0 + 0]));
          st.y = f2bf(sigf(acc[s][q][1] + biass[k0 + 1]));
          st.z = f2bf(sigf(acc[s][q][2] + biass[k0 + 2]));
          st.w = f2bf(sigf(acc[s][q][3] + biass[k0 + 3]));
          *(ushort4*)&actB[p * AS + k0] = st;
        }
    }
    __syncthreads();

    {
      f32x4 acc[2][4] = {};
#pragma unroll
      for (int t = 0; t < 4; ++t) {
        int col = (t << 5) + colb;
        bf16x8 a[2], b[4];
#pragma unroll
        for (int s = 0; s < 2; ++s)
          a[s] = cvt8(wr1[(s * 4 + t) * 2], wr1[(s * 4 + t) * 2 + 1]);
#pragma unroll
        for (int q = 0; q < 4; ++q)
          b[q] = *(const bf16x8*)&actB[(q * 16 + l15) * AS + col];
#pragma unroll
        for (int s = 0; s < 2; ++s)
#pragma unroll
          for (int q = 0; q < 4; ++q)
            acc[s][q] = __builtin_amdgcn_mfma_f32_16x16x32_bf16(a[s], b[q], acc[s][q], 0, 0, 0);
      }
#pragma unroll
      for (int s = 0; s < 2; ++s)
#pragma unroll
        for (int q = 0; q < 4; ++q) {
          int p = q * 16 + l15;
          int k0 = wv * 32 + s * 16 + (l4 << 2);
          ushort4 st;
          st.x = f2bf(sigf(acc[s][q][0] + biass[128 + k0 + 0]));
          st.y = f2bf(sigf(acc[s][q][1] + biass[128 + k0 + 1]));
          st.z = f2bf(sigf(acc[s][q][2] + biass[128 + k0 + 2]));
          st.w = f2bf(sigf(acc[s][q][3] + biass[128 + k0 + 3]));
          *(ushort4*)&actA[p * AS + k0] = st;
        }
    }
    __syncthreads();

    {
      f32x4 acc[2][4] = {};
#pragma unroll
      for (int t = 0; t < 4; ++t) {
        int col = (t << 5) + colb;
        bf16x8 a[2], b[4];
#pragma unroll
        for (int s = 0; s < 2; ++s)
          a[s] = cvt8(wr2[(s * 4 + t) * 2], wr2[(s * 4 + t) * 2 + 1]);
#pragma unroll
        for (int q = 0; q < 4; ++q)
          b[q] = *(const bf16x8*)&actA[(q * 16 + l15) * AS + col];
#pragma unroll
        for (int s = 0; s < 2; ++s)
#pragma unroll
          for (int q = 0; q < 4; ++q)
            acc[s][q] = __builtin_amdgcn_mfma_f32_16x16x32_bf16(a[s], b[q], acc[s][q], 0, 0, 0);
      }
#pragma unroll
      for (int s = 0; s < 2; ++s)
#pragma unroll
        for (int q = 0; q < 4; ++q) {
          int p = q * 16 + l15;
          int k0 = wv * 32 + s * 16 + (l4 << 2);
          ushort4 st;
          st.x = f2bf(sigf(acc[s][q][0] + biass[256 + k0 + 0]));
          st.y = f2bf(sigf(acc[s][q][1] + biass[256 + k0 + 1]));
          st.z = f2bf(sigf(acc[s][q][2] + biass[256 + k0 + 2]));
          st.w = f2bf(sigf(acc[s][q][3] + biass[256 + k0 + 3]));
          *(ushort4*)&u1bf[((size_t)j * MPTS + p) * WIDTH + k0] = st;
        }
    }
  } else {
    // ---------------- transpose branch ----------------
    float* ts = (float*)smem;                // 9,472 B
    int t = bid - 33;                        // [0, 2080)
    if (t < 512 && tid < 64) {               // zero out (512 x 1KB)
      float4 z = {0.f, 0.f, 0.f, 0.f};
      *(float4*)&out[((size_t)t << 8) + (tid << 2)] = z;
    }
    int qt = t % 65, mt = t / 65;
    int qb = qt * 32;
    int mb = mt * 64;
#pragma unroll
    for (int c = tid; c < 512; c += 256) {
      int row = c >> 3, c8 = c & 7;
      float4 v = *(const float4*)&xi[(size_t)(mb + row) * NQ + qb + (c8 << 2)];
      ts[row * 37 + (c8 << 2) + 0] = v.x;
      ts[row * 37 + (c8 << 2) + 1] = v.y;
      ts[row * 37 + (c8 << 2) + 2] = v.z;
      ts[row * 37 + (c8 << 2) + 3] = v.w;
    }
    __syncthreads();
#pragma unroll
    for (int c = tid; c < 512; c += 256) {
      int r = c >> 4, mq = c & 15;
      ushort4 h;
      h.x = f2bf(ts[(mq * 4 + 0) * 37 + r]);
      h.y = f2bf(ts[(mq * 4 + 1) * 37 + r]);
      h.z = f2bf(ts[(mq * 4 + 2) * 37 + r]);
      h.w = f2bf(ts[(mq * 4 + 3) * 37 + r]);
      *(ushort4*)&xiT[((size_t)mt * NQ + (qb + r)) * 64 + (mq << 2)] = h;
    }
  }
}

// ------------- phase B: Gt2 in k_conv staging order -----------------------
// Gt2[region = mp*2+half][j=33][g=4][p=64][8m], region = 67,584 shorts.
__global__ __launch_bounds__(256) void k_final(const float* __restrict__ wf,
                                               const float* __restrict__ bfin,
                                               const unsigned short* __restrict__ u1bf,
                                               unsigned short* __restrict__ Gt2) {
  constexpr int KP = 136;
  __shared__ unsigned short As[64 * KP];
  __shared__ unsigned short Bs[64 * KP];
  __shared__ float bfs[64];
  int bid = blockIdx.x;                    // 33*32
  int j = bid >> 5;
  int m0 = (bid & 31) << 6;
#pragma unroll
  for (int c = threadIdx.x; c < 64 * 32; c += 256) {
    int row = c >> 5, f4 = c & 31;
    float4 v = *(const float4*)(wf + ((size_t)(m0 + row) * WIN + j) * WIDTH + (f4 << 2));
    ushort4 h;
    h.x = f2bf(v.x); h.y = f2bf(v.y); h.z = f2bf(v.z); h.w = f2bf(v.w);
    *(ushort4*)(&As[row * KP + (f4 << 2)]) = h;
  }
#pragma unroll
  for (int c = threadIdx.x; c < 64 * 16; c += 256) {
    int p = c >> 4, ch = c & 15;
    uint4 v = *(const uint4*)(u1bf + (size_t)(j * MPTS + p) * WIDTH + (ch << 3));
    *(uint4*)(&Bs[p * KP + (ch << 3)]) = v;
  }
  if (threadIdx.x < 64) bfs[threadIdx.x] = bfin[(size_t)(m0 + threadIdx.x) * WIN + j];
  __syncthreads();
  int wv = threadIdx.x >> 6, lane = threadIdx.x & 63;
  int l15 = lane & 15, l4 = lane >> 4;
  f32x4 acc[4] = {};
#pragma unroll
  for (int t = 0; t < 4; ++t) {
    int col = (t << 5) + (l4 << 3);
    bf16x8 a = *(const bf16x8*)(&As[(wv * 16 + l15) * KP + col]);
#pragma unroll
    for (int q = 0; q < 4; ++q) {
      bf16x8 bb = *(const bf16x8*)(&Bs[(q * 16 + l15) * KP + col]);
      acc[q] = __builtin_amdgcn_mfma_f32_16x16x32_bf16(a, bb, acc[q], 0, 0, 0);
    }
  }
  size_t region = (size_t)((bid & 31) << 1) + (wv >> 1);
  int g = ((wv & 1) << 1) + (l4 >> 1);
  int m8 = (l4 & 1) << 2;
  int mb = wv * 16 + (l4 << 2);
#pragma unroll
  for (int q = 0; q < 4; ++q) {
    int p = q * 16 + l15;
    float z0 = acc[q][0] + bfs[mb + 0];
    float z1 = acc[q][1] + bfs[mb + 1];
    float z2 = acc[q][2] + bfs[mb + 2];
    float z3 = acc[q][3] + bfs[mb + 3];
    ushort4 st;
    st.x = f2bf(sigf(z0)); st.y = f2bf(sigf(z1));
    st.z = f2bf(sigf(z2)); st.w = f2bf(sigf(z3));
    *(ushort4*)(&Gt2[region * 67584 + ((size_t)(j * 4 + g) * 64 + p) * 8 + m8]) = st;
  }
}

// ------------- phase C: out[n,p] += sum_{j,m} xiT[n+j,m] * Gt2[j,p,m] ------
// R11: LDS-traffic reduction. Model (validated: measured MfmaUtil 12-14% ==
// predicted 2.2us MFMA / 15.8us LDS-reads): kernel is ds_read-throughput
// bound at 0.75 reads/MFMA. New decomposition: 11 phases x 6 (j,half) units;
// waves = 2 n-halves x 2 j-parities; wave tile 64n x 64p (acc[4][4]).
// Per unit: 4 A + 4 B reads feed 16 MFMA -> 0.5 reads/MFMA (x2/3 traffic).
// Every wave gets EXACTLY 3 units/phase (slots pj, pj+2, pj+4): compile-time
// trip counts, no predication, perfect balance (fixes R6). Epilogue: both
// parity waves atomicAdd same outputs (no reduction pass). Counted-vmcnt
// barrier discipline from R10 kept. LDS = 20,480 + 2*24,576 = 69,632 B.
__global__ __launch_bounds__(256) void k_conv(const unsigned short* __restrict__ xiT,
                                              const unsigned short* __restrict__ Gt2,
                                              float* __restrict__ out) {
  extern __shared__ unsigned short lds[];
  unsigned short* As = lds;                // [160][64] swizzled = 20,480 B
  unsigned short* Bb0 = lds + 10240;       // B buffers: 12,288 shorts each
  int bid = blockIdx.x;
  int mp = bid & 31;                       // bid%8 == mp%8 -> XCD-shared B
  int n0 = (bid >> 5) << 7;
  int tid = threadIdx.x;
  int wv = tid >> 6, lane = tid & 63, l15 = lane & 15, l4 = lane >> 4;
  int wn = wv & 1;                         // n-half: rows [wn*64, wn*64+64)
  int pj = wv >> 1;                        // unit parity

  // ---- stage A once (5 instr/wave): contiguous 1KB; XOR permute c^=row&7
  const unsigned short* Abase = xiT + (size_t)mp * (NQ * 64) + (size_t)n0 * 64;
#pragma unroll
  for (int k = 0; k < 5; ++k) {
    int instr = wv * 5 + k;
    int s = (instr << 6) + lane;
    int row = s >> 3;
    int c = (s & 7) ^ (row & 7);
    gll16(Abase + (size_t)row * 64 + (c << 3), As + (instr << 9));
  }

  const unsigned short* Rb = Gt2 + (size_t)(mp << 1) * 67584;  // region pair

  // unit u in [0,66): half = u>=33, j = u - 33*half; 2048 shorts per unit.
  // ---- prologue: stage phase 0 (units 0..5) into buf0, 6 instr/wave
#pragma unroll
  for (int k = 0; k < 6; ++k) {
    int i = wv * 6 + k;                    // 24 instrs, 512 shorts each
    int uu = i >> 2;                       // unit 0..5 (phase 0: u = uu)
    const unsigned short* us = Rb + ((size_t)uu << 11);  // all units <33
    gll16(us + ((i & 3) << 9) + (lane << 3), Bb0 + (i << 9));
  }

  f32x4 acc[4][4] = {};
#pragma unroll
  for (int t = 0; t < 11; ++t) {
    // ---- issue phase t+1 staging (buf[(t+1)&1]); readers of that buffer
    //      finished at barrier#2 of phase t-1.
    if (t < 10) {
#pragma unroll
      for (int k = 0; k < 6; ++k) {
        int i = wv * 6 + k;
        int uu = 6 * (t + 1) + (i >> 2);
        int hf = (uu >= 33);
        int jj = uu - (hf ? 33 : 0);
        const unsigned short* us = Rb + (size_t)hf * 67584 + ((size_t)jj << 11);
        gll16(us + ((i & 3) << 9) + (lane << 3),
              Bb0 + ((t + 1) & 1) * 12288 + (i << 9));
      }
    }
    __builtin_amdgcn_sched_barrier(0);
    if (t == 10) asm volatile("s_waitcnt vmcnt(0)");
    else         asm volatile("s_waitcnt vmcnt(6)");   // drain B(t) (+A at t=0)
    __builtin_amdgcn_sched_barrier(0);
    __builtin_amdgcn_s_barrier();          // #1: B(t) visible to all waves

    // ---- compute: this wave's 3 units (slots pj, pj+2, pj+4)
    {
      const unsigned short* Bs = Bb0 + (t & 1) * 12288;
      bf16x8 a[4], b[4];
      // load unit k=0
      {
        int u0 = 6 * t + pj;
        int hf = (u0 >= 33);
        int j0 = u0 - (hf ? 33 : 0);
        int h4 = hf << 2;
#pragma unroll
        for (int g = 0; g < 4; ++g) {
          int row = wn * 64 + (g << 4) + l15 + j0;
          a[g] = *(const bf16x8*)&As[row * 64 + (((h4 | l4) ^ (row & 7)) << 3)];
        }
#pragma unroll
        for (int q = 0; q < 4; ++q)
          b[q] = *(const bf16x8*)&Bs[(size_t)pj * 2048 + (l4 << 9) + (((q << 4) + l15) << 3)];
      }
#pragma unroll
      for (int k = 0; k < 3; ++k) {
        bf16x8 an[4], bn[4];
        if (k < 2) {                       // prefetch next unit
          int un = 6 * t + pj + 2 * (k + 1);
          int hf = (un >= 33);
          int jn = un - (hf ? 33 : 0);
          int h4 = hf << 2;
#pragma unroll
          for (int g = 0; g < 4; ++g) {
            int row = wn * 64 + (g << 4) + l15 + jn;
            an[g] = *(const bf16x8*)&As[row * 64 + (((h4 | l4) ^ (row & 7)) << 3)];
          }
          int slot = pj + 2 * (k + 1);
#pragma unroll
          for (int q = 0; q < 4; ++q)
            bn[q] = *(const bf16x8*)&Bs[(size_t)slot * 2048 + (l4 << 9) + (((q << 4) + l15) << 3)];
        }
#pragma unroll
        for (int g = 0; g < 4; ++g)
#pragma unroll
          for (int q = 0; q < 4; ++q)
            acc[g][q] = __builtin_amdgcn_mfma_f32_16x16x32_bf16(a[g], b[q], acc[g][q], 0, 0, 0);
#pragma unroll
        for (int g = 0; g < 4; ++g) a[g] = an[g];
#pragma unroll
        for (int q = 0; q < 4; ++q) b[q] = bn[q];
      }
    }
    __builtin_amdgcn_s_barrier();          // #2: all waves done with buf[t&1]
  }

  // ---- epilogue: both parity waves atomicAdd the same (n,p) — correct sum
#pragma unroll
  for (int g = 0; g < 4; ++g)
#pragma unroll
    for (int q = 0; q < 4; ++q) {
      int nr = n0 + wn * 64 + (g << 4) + (l4 << 2);
      int p = (q << 4) + l15;
#pragma unroll
      for (int i = 0; i < 4; ++i)
        atomicAdd(&out[(size_t)(nr + i) * MPTS + p], acc[g][q][i]);
    }
}

extern "C" void kernel_launch(void* const* d_in, const int* in_sizes, int n_in,
                              void* d_out, int out_size, void* d_ws, size_t ws_size,
                              hipStream_t stream) {
  const float* u    = (const float*)d_in[0];  // [64,64]
  const float* w0   = (const float*)d_in[1];  // [33,128,64]
  const float* b0   = (const float*)d_in[2];  // [33,128,1]
  const float* w    = (const float*)d_in[3];  // [2,33,128,128]
  const float* bias = (const float*)d_in[4];  // [2,33,128,1]
  const float* wf   = (const float*)d_in[5];  // [2048,33,128]
  const float* bfin = (const float*)d_in[6];  // [2048,33,1]
  const float* xi   = (const float*)d_in[7];  // [2048,2080]
  float* out = (float*)d_out;                 // [2048,64]
  char* ws = (char*)d_ws;
  unsigned short* xiT  = (unsigned short*)(ws);             // 8,519,680 B
  unsigned short* Gt2  = (unsigned short*)(ws + 8519680);   // 8,650,752 B
  unsigned short* u1bf = (unsigned short*)(ws + 17170432);  // 540,672 B

  hipFuncSetAttribute(reinterpret_cast<const void*>(&k_prep),
                      hipFuncAttributeMaxDynamicSharedMemorySize, 36352);
  hipFuncSetAttribute(reinterpret_cast<const void*>(&k_conv),
                      hipFuncAttributeMaxDynamicSharedMemorySize, 69632);

  k_prep<<<2113, 256, 36352, stream>>>(xi, xiT, u, w0, b0, w, bias, u1bf, out);
  k_final<<<33 * 32, 256, 0, stream>>>(wf, bfin, u1bf, Gt2);
  k_conv<<<512, 256, 69632, stream>>>(xiT, Gt2, out);
}

// Round 12
// 149.770 us; speedup vs baseline: 1.1132x; 1.1132x over previous
//
#include <hip/hip_runtime.h>

#define WIN 33
#define WIDTH 128
#define MPTS 64
#define NN 2048
#define MM 2048
#define DD 64
#define NQ 2080   // N + 2L

typedef __bf16 bf16x8 __attribute__((ext_vector_type(8)));
typedef float f32x4 __attribute__((ext_vector_type(4)));

__device__ __forceinline__ unsigned short f2bf(float x) {
  union { float f; unsigned int u; } v; v.f = x;
  unsigned int r = v.u + 0x7FFFu + ((v.u >> 16) & 1u);  // RNE
  return (unsigned short)(r >> 16);
}
__device__ __forceinline__ float sigf(float x) { return 1.0f / (1.0f + __expf(-x)); }

// async global->LDS, 16B per lane, fire-and-forget (tracked by vmcnt)
__device__ __forceinline__ void gll16(const unsigned short* g, unsigned short* l) {
  __builtin_amdgcn_global_load_lds(
      (const __attribute__((address_space(1))) unsigned int*)g,
      (__attribute__((address_space(3))) unsigned int*)l, 16, 0, 0);
}

__device__ __forceinline__ bf16x8 cvt8(const float4& a, const float4& b) {
  union { bf16x8 v; unsigned short s[8]; } u;
  u.s[0] = f2bf(a.x); u.s[1] = f2bf(a.y); u.s[2] = f2bf(a.z); u.s[3] = f2bf(a.w);
  u.s[4] = f2bf(b.x); u.s[5] = f2bf(b.y); u.s[6] = f2bf(b.z); u.s[7] = f2bf(b.w);
  return u.v;
}

// ------------- MLP: own kernel, 33 blocks, launch_bounds(256,1) ------------
// R12: R11's k_prep VGPR_Count=92 proved the R9 weight-prefetch (needs ~160
// VGPR for wr0/wr1/wr2) was SUNK by the allocator back to the uses — the
// serial load-latency chain never went away (R9 neutral). Separate kernel
// with min-waves/EU=1 gives a 512-VGPR budget so the prefetch is held.
// 33 blocks -> occupancy irrelevant. Structure identical to R9's MLP branch.
__global__ __launch_bounds__(256, 1) void k_mlp(const float* __restrict__ u,
                                                const float* __restrict__ w0,
                                                const float* __restrict__ b0,
                                                const float* __restrict__ w,
                                                const float* __restrict__ bias,
                                                unsigned short* __restrict__ u1bf) {
  constexpr int AS = 136;
  __shared__ float biass[384];
  __shared__ unsigned short actA[64 * AS];
  __shared__ unsigned short actB[64 * AS];
  int j = blockIdx.x;
  int tid = threadIdx.x;
  int wv = tid >> 6, lane = tid & 63, l15 = lane & 15, l4 = lane >> 4;
  int colb = l4 << 3;

  const float* wb0 = w + (size_t)j * 16384;
  const float* wb1 = w + (size_t)(WIN + j) * 16384;

  float4 wr0[8], wr1[16], wr2[16];

  // ---- Phase A: stage u -> actA; issue w0 + w1 loads; all biases
  {
    float4 ureg[4];
#pragma unroll
    for (int r = 0; r < 4; ++r) {
      int c = tid + (r << 8);
      ureg[r] = *(const float4*)&u[(size_t)(c >> 4) * DD + ((c & 15) << 2)];
    }
#pragma unroll
    for (int s = 0; s < 2; ++s)
#pragma unroll
      for (int t = 0; t < 2; ++t) {        // w0: [33][128][64]
        int row = wv * 32 + s * 16 + l15, col = (t << 5) + colb;
        const float* p = &w0[((size_t)j * 128 + row) * 64 + col];
        wr0[(s * 2 + t) * 2 + 0] = *(const float4*)p;
        wr0[(s * 2 + t) * 2 + 1] = *(const float4*)(p + 4);
      }
#pragma unroll
    for (int s = 0; s < 2; ++s)
#pragma unroll
      for (int t = 0; t < 4; ++t) {        // w (layer1): [128][128]
        int row = wv * 32 + s * 16 + l15, col = (t << 5) + colb;
        const float* p = &wb0[(size_t)row * 128 + col];
        wr1[(s * 4 + t) * 2 + 0] = *(const float4*)p;
        wr1[(s * 4 + t) * 2 + 1] = *(const float4*)(p + 4);
      }
    if (tid < 128) {
      biass[tid]       = b0[j * 128 + tid];
      biass[128 + tid] = bias[(size_t)j * 128 + tid];
      biass[256 + tid] = bias[(size_t)(WIN + j) * 128 + tid];
    }
#pragma unroll
    for (int r = 0; r < 4; ++r) {
      int c = tid + (r << 8);
      float4 v = ureg[r];
      ushort4 h; h.x = f2bf(v.x); h.y = f2bf(v.y); h.z = f2bf(v.z); h.w = f2bf(v.w);
      *(ushort4*)&actA[(c >> 4) * AS + ((c & 15) << 2)] = h;
    }
  }
  __syncthreads();

  // ---- Phase B: issue w2; compute L0 (K=64); sig -> actB
#pragma unroll
  for (int s = 0; s < 2; ++s)
#pragma unroll
    for (int t = 0; t < 4; ++t) {          // w (layer2): [128][128]
      int row = wv * 32 + s * 16 + l15, col = (t << 5) + colb;
      const float* p = &wb1[(size_t)row * 128 + col];
      wr2[(s * 4 + t) * 2 + 0] = *(const float4*)p;
      wr2[(s * 4 + t) * 2 + 1] = *(const float4*)(p + 4);
    }
  {
    f32x4 acc[2][4] = {};
#pragma unroll
    for (int t = 0; t < 2; ++t) {
      int col = (t << 5) + colb;
      bf16x8 a[2], b[4];
#pragma unroll
      for (int s = 0; s < 2; ++s)
        a[s] = cvt8(wr0[(s * 2 + t) * 2], wr0[(s * 2 + t) * 2 + 1]);
#pragma unroll
      for (int q = 0; q < 4; ++q)
        b[q] = *(const bf16x8*)&actA[(q * 16 + l15) * AS + col];
#pragma unroll
      for (int s = 0; s < 2; ++s)
#pragma unroll
        for (int q = 0; q < 4; ++q)
          acc[s][q] = __builtin_amdgcn_mfma_f32_16x16x32_bf16(a[s], b[q], acc[s][q], 0, 0, 0);
    }
#pragma unroll
    for (int s = 0; s < 2; ++s)
#pragma unroll
      for (int q = 0; q < 4; ++q) {
        int p = q * 16 + l15;
        int k0 = wv * 32 + s * 16 + (l4 << 2);
        ushort4 st;
        st.x = f2bf(sigf(acc[s][q][0] + biass[k0 + 0]));
        st.y = f2bf(sigf(acc[s][q][1] + biass[k0 + 1]));
        st.z = f2bf(sigf(acc[s][q][2] + biass[k0 + 2]));
        st.w = f2bf(sigf(acc[s][q][3] + biass[k0 + 3]));
        *(ushort4*)&actB[p * AS + k0] = st;
      }
  }
  __syncthreads();

  // ---- Phase C: compute L1 (K=128); sig -> actA
  {
    f32x4 acc[2][4] = {};
#pragma unroll
    for (int t = 0; t < 4; ++t) {
      int col = (t << 5) + colb;
      bf16x8 a[2], b[4];
#pragma unroll
      for (int s = 0; s < 2; ++s)
        a[s] = cvt8(wr1[(s * 4 + t) * 2], wr1[(s * 4 + t) * 2 + 1]);
#pragma unroll
      for (int q = 0; q < 4; ++q)
        b[q] = *(const bf16x8*)&actB[(q * 16 + l15) * AS + col];
#pragma unroll
      for (int s = 0; s < 2; ++s)
#pragma unroll
        for (int q = 0; q < 4; ++q)
          acc[s][q] = __builtin_amdgcn_mfma_f32_16x16x32_bf16(a[s], b[q], acc[s][q], 0, 0, 0);
    }
#pragma unroll
    for (int s = 0; s < 2; ++s)
#pragma unroll
      for (int q = 0; q < 4; ++q) {
        int p = q * 16 + l15;
        int k0 = wv * 32 + s * 16 + (l4 << 2);
        ushort4 st;
        st.x = f2bf(sigf(acc[s][q][0] + biass[128 + k0 + 0]));
        st.y = f2bf(sigf(acc[s][q][1] + biass[128 + k0 + 1]));
        st.z = f2bf(sigf(acc[s][q][2] + biass[128 + k0 + 2]));
        st.w = f2bf(sigf(acc[s][q][3] + biass[128 + k0 + 3]));
        *(ushort4*)&actA[p * AS + k0] = st;
      }
  }
  __syncthreads();

  // ---- Phase D: compute L2 (K=128); sig -> u1bf (global, no LDS trip)
  {
    f32x4 acc[2][4] = {};
#pragma unroll
    for (int t = 0; t < 4; ++t) {
      int col = (t << 5) + colb;
      bf16x8 a[2], b[4];
#pragma unroll
      for (int s = 0; s < 2; ++s)
        a[s] = cvt8(wr2[(s * 4 + t) * 2], wr2[(s * 4 + t) * 2 + 1]);
#pragma unroll
      for (int q = 0; q < 4; ++q)
        b[q] = *(const bf16x8*)&actA[(q * 16 + l15) * AS + col];
#pragma unroll
      for (int s = 0; s < 2; ++s)
#pragma unroll
        for (int q = 0; q < 4; ++q)
          acc[s][q] = __builtin_amdgcn_mfma_f32_16x16x32_bf16(a[s], b[q], acc[s][q], 0, 0, 0);
    }
#pragma unroll
    for (int s = 0; s < 2; ++s)
#pragma unroll
      for (int q = 0; q < 4; ++q) {
        int p = q * 16 + l15;
        int k0 = wv * 32 + s * 16 + (l4 << 2);
        ushort4 st;
        st.x = f2bf(sigf(acc[s][q][0] + biass[256 + k0 + 0]));
        st.y = f2bf(sigf(acc[s][q][1] + biass[256 + k0 + 1]));
        st.z = f2bf(sigf(acc[s][q][2] + biass[256 + k0 + 2]));
        st.w = f2bf(sigf(acc[s][q][3] + biass[256 + k0 + 3]));
        *(ushort4*)&u1bf[((size_t)j * MPTS + p) * WIDTH + k0] = st;
      }
  }
}

// ------------- transpose: xi[M][NQ] f32 -> xiT[mp][q][64m] bf16 + out-zero -
__global__ __launch_bounds__(256) void k_prep(const float* __restrict__ xi,
                                              unsigned short* __restrict__ xiT,
                                              float* __restrict__ out) {
  __shared__ float ts[64 * 37];            // 9,472 B
  int t = blockIdx.x;                      // [0, 2080)
  int tid = threadIdx.x;
  if (t < 512 && tid < 64) {               // zero out (512 x 1KB)
    float4 z = {0.f, 0.f, 0.f, 0.f};
    *(float4*)&out[((size_t)t << 8) + (tid << 2)] = z;
  }
  int qt = t % 65, mt = t / 65;
  int qb = qt * 32;
  int mb = mt * 64;
#pragma unroll
  for (int c = tid; c < 512; c += 256) {
    int row = c >> 3, c8 = c & 7;
    float4 v = *(const float4*)&xi[(size_t)(mb + row) * NQ + qb + (c8 << 2)];
    ts[row * 37 + (c8 << 2) + 0] = v.x;
    ts[row * 37 + (c8 << 2) + 1] = v.y;
    ts[row * 37 + (c8 << 2) + 2] = v.z;
    ts[row * 37 + (c8 << 2) + 3] = v.w;
  }
  __syncthreads();
#pragma unroll
  for (int c = tid; c < 512; c += 256) {
    int r = c >> 4, mq = c & 15;
    ushort4 h;
    h.x = f2bf(ts[(mq * 4 + 0) * 37 + r]);
    h.y = f2bf(ts[(mq * 4 + 1) * 37 + r]);
    h.z = f2bf(ts[(mq * 4 + 2) * 37 + r]);
    h.w = f2bf(ts[(mq * 4 + 3) * 37 + r]);
    *(ushort4*)&xiT[((size_t)mt * NQ + (qb + r)) * 64 + (mq << 2)] = h;
  }
}

// ------------- phase B: Gt2 in k_conv staging order -----------------------
// Gt2[region = mp*2+half][j=33][g=4][p=64][8m], region = 67,584 shorts.
__global__ __launch_bounds__(256) void k_final(const float* __restrict__ wf,
                                               const float* __restrict__ bfin,
                                               const unsigned short* __restrict__ u1bf,
                                               unsigned short* __restrict__ Gt2) {
  constexpr int KP = 136;
  __shared__ unsigned short As[64 * KP];
  __shared__ unsigned short Bs[64 * KP];
  __shared__ float bfs[64];
  int bid = blockIdx.x;                    // 33*32
  int j = bid >> 5;
  int m0 = (bid & 31) << 6;
#pragma unroll
  for (int c = threadIdx.x; c < 64 * 32; c += 256) {
    int row = c >> 5, f4 = c & 31;
    float4 v = *(const float4*)(wf + ((size_t)(m0 + row) * WIN + j) * WIDTH + (f4 << 2));
    ushort4 h;
    h.x = f2bf(v.x); h.y = f2bf(v.y); h.z = f2bf(v.z); h.w = f2bf(v.w);
    *(ushort4*)(&As[row * KP + (f4 << 2)]) = h;
  }
#pragma unroll
  for (int c = threadIdx.x; c < 64 * 16; c += 256) {
    int p = c >> 4, ch = c & 15;
    uint4 v = *(const uint4*)(u1bf + (size_t)(j * MPTS + p) * WIDTH + (ch << 3));
    *(uint4*)(&Bs[p * KP + (ch << 3)]) = v;
  }
  if (threadIdx.x < 64) bfs[threadIdx.x] = bfin[(size_t)(m0 + threadIdx.x) * WIN + j];
  __syncthreads();
  int wv = threadIdx.x >> 6, lane = threadIdx.x & 63;
  int l15 = lane & 15, l4 = lane >> 4;
  f32x4 acc[4] = {};
#pragma unroll
  for (int t = 0; t < 4; ++t) {
    int col = (t << 5) + (l4 << 3);
    bf16x8 a = *(const bf16x8*)(&As[(wv * 16 + l15) * KP + col]);
#pragma unroll
    for (int q = 0; q < 4; ++q) {
      bf16x8 bb = *(const bf16x8*)(&Bs[(q * 16 + l15) * KP + col]);
      acc[q] = __builtin_amdgcn_mfma_f32_16x16x32_bf16(a, bb, acc[q], 0, 0, 0);
    }
  }
  size_t region = (size_t)((bid & 31) << 1) + (wv >> 1);
  int g = ((wv & 1) << 1) + (l4 >> 1);
  int m8 = (l4 & 1) << 2;
  int mb = wv * 16 + (l4 << 2);
#pragma unroll
  for (int q = 0; q < 4; ++q) {
    int p = q * 16 + l15;
    float z0 = acc[q][0] + bfs[mb + 0];
    float z1 = acc[q][1] + bfs[mb + 1];
    float z2 = acc[q][2] + bfs[mb + 2];
    float z3 = acc[q][3] + bfs[mb + 3];
    ushort4 st;
    st.x = f2bf(sigf(z0)); st.y = f2bf(sigf(z1));
    st.z = f2bf(sigf(z2)); st.w = f2bf(sigf(z3));
    *(ushort4*)(&Gt2[region * 67584 + ((size_t)(j * 4 + g) * 64 + p) * 8 + m8]) = st;
  }
}

// ------------- phase C: out[n,p] += sum_{j,m} xiT[n+j,m] * Gt2[j,p,m] ------
// R10-exact (best measured config, 145.5us total). Counted-vmcnt two-barrier
// pipeline; Bs double-buffered; layouts/swizzle/compute unchanged.
__global__ __launch_bounds__(256) void k_conv(const unsigned short* __restrict__ xiT,
                                              const unsigned short* __restrict__ Gt2,
                                              float* __restrict__ out) {
  extern __shared__ unsigned short lds[];
  unsigned short* As = lds;                // [160][64] swizzled = 20,480 B
  int bid = blockIdx.x;
  int mp = bid & 31;                       // bid%8 == mp%8 -> XCD-shared B
  int n0 = (bid >> 5) << 7;
  int tid = threadIdx.x;
  int wv = tid >> 6, lane = tid & 63, l15 = lane & 15, l4 = lane >> 4;

  const unsigned short* Abase = xiT + (size_t)mp * (NQ * 64) + (size_t)n0 * 64;
#pragma unroll
  for (int k = 0; k < 5; ++k) {
    int instr = wv * 5 + k;
    int s = (instr << 6) + lane;
    int row = s >> 3;
    int c = (s & 7) ^ (row & 7);
    gll16(Abase + (size_t)row * 64 + (c << 3), As + (instr << 9));
  }

  constexpr int JBT[10]  = {0, 7, 14, 21, 28, 0, 7, 14, 21, 28};
  constexpr int CNTT[10] = {7, 7, 7, 7, 5, 7, 7, 7, 7, 5};
  constexpr int HFT[10]  = {0, 0, 0, 0, 0, 1, 1, 1, 1, 1};

  const unsigned short* Rb0 = Gt2 + (size_t)(mp << 1) * 67584;
  const unsigned short* Rb1 = Gt2 + (size_t)((mp << 1) + 1) * 67584;

  {
    const unsigned short* Bb = Rb0;
#pragma unroll
    for (int k = 0; k < 7; ++k) {
      int instr = wv * 7 + k;
      gll16(Bb + (((instr << 6) + lane) << 3), lds + 10240 + (instr << 9));
    }
  }

  f32x4 acc[2][4] = {};
#pragma unroll
  for (int t = 0; t < 10; ++t) {
    if (t < 9) {
      const int jbn = JBT[t + 1], cntn = CNTT[t + 1];
      const unsigned short* Bb =
          (HFT[t + 1] ? Rb1 : Rb0) + ((size_t)jbn << 11);
      unsigned short* Bst = lds + 10240 + ((t + 1) & 1) * 14336;
#pragma unroll
      for (int k = 0; k < cntn; ++k) {
        int instr = wv * cntn + k;
        gll16(Bb + (((instr << 6) + lane) << 3), Bst + (instr << 9));
      }
    }
    __builtin_amdgcn_sched_barrier(0);
    if (t == 9)                asm volatile("s_waitcnt vmcnt(0)");
    else if (CNTT[t + 1] == 7) asm volatile("s_waitcnt vmcnt(7)");
    else                       asm volatile("s_waitcnt vmcnt(5)");
    __builtin_amdgcn_sched_barrier(0);
    __builtin_amdgcn_s_barrier();
    {
      const int jb = JBT[t], cnt = CNTT[t], h4 = HFT[t] << 2;
      const unsigned short* Bs = lds + 10240 + (t & 1) * 14336;
      bf16x8 a[2], b[4];
#pragma unroll
      for (int s = 0; s < 2; ++s) {
        int row = wv * 32 + s * 16 + l15 + jb;
        a[s] = *(const bf16x8*)&As[row * 64 + (((h4 | l4) ^ (row & 7)) << 3)];
      }
#pragma unroll
      for (int q = 0; q < 4; ++q) {
        int slot = (l4 << 6) + (q << 4) + l15;
        b[q] = *(const bf16x8*)&Bs[slot << 3];
      }
#pragma unroll
      for (int jj = 0; jj < cnt; ++jj) {
        bf16x8 an[2], bn[4];
        if (jj < cnt - 1) {
#pragma unroll
          for (int s = 0; s < 2; ++s) {
            int row = wv * 32 + s * 16 + l15 + jb + jj + 1;
            an[s] = *(const bf16x8*)&As[row * 64 + (((h4 | l4) ^ (row & 7)) << 3)];
          }
#pragma unroll
          for (int q = 0; q < 4; ++q) {
            int slot = ((((jj + 1) << 2) + l4) << 6) + (q << 4) + l15;
            bn[q] = *(const bf16x8*)&Bs[slot << 3];
          }
        }
#pragma unroll
        for (int s = 0; s < 2; ++s)
#pragma unroll
          for (int q = 0; q < 4; ++q)
            acc[s][q] = __builtin_amdgcn_mfma_f32_16x16x32_bf16(a[s], b[q], acc[s][q], 0, 0, 0);
#pragma unroll
        for (int s = 0; s < 2; ++s) a[s] = an[s];
#pragma unroll
        for (int q = 0; q < 4; ++q) b[q] = bn[q];
      }
    }
    __builtin_amdgcn_s_barrier();
  }
#pragma unroll
  for (int s = 0; s < 2; ++s)
#pragma unroll
    for (int q = 0; q < 4; ++q) {
      int nr = n0 + wv * 32 + s * 16 + (l4 << 2);
      int p = q * 16 + l15;
#pragma unroll
      for (int i = 0; i < 4; ++i)
        atomicAdd(&out[(size_t)(nr + i) * MPTS + p], acc[s][q][i]);
    }
}

extern "C" void kernel_launch(void* const* d_in, const int* in_sizes, int n_in,
                              void* d_out, int out_size, void* d_ws, size_t ws_size,
                              hipStream_t stream) {
  const float* u    = (const float*)d_in[0];  // [64,64]
  const float* w0   = (const float*)d_in[1];  // [33,128,64]
  const float* b0   = (const float*)d_in[2];  // [33,128,1]
  const float* w    = (const float*)d_in[3];  // [2,33,128,128]
  const float* bias = (const float*)d_in[4];  // [2,33,128,1]
  const float* wf   = (const float*)d_in[5];  // [2048,33,128]
  const float* bfin = (const float*)d_in[6];  // [2048,33,1]
  const float* xi   = (const float*)d_in[7];  // [2048,2080]
  float* out = (float*)d_out;                 // [2048,64]
  char* ws = (char*)d_ws;
  unsigned short* xiT  = (unsigned short*)(ws);             // 8,519,680 B
  unsigned short* Gt2  = (unsigned short*)(ws + 8519680);   // 8,650,752 B
  unsigned short* u1bf = (unsigned short*)(ws + 17170432);  // 540,672 B

  hipFuncSetAttribute(reinterpret_cast<const void*>(&k_conv),
                      hipFuncAttributeMaxDynamicSharedMemorySize, 77824);

  k_mlp<<<WIN, 256, 0, stream>>>(u, w0, b0, w, bias, u1bf);
  k_prep<<<2080, 256, 0, stream>>>(xi, xiT, out);
  k_final<<<33 * 32, 256, 0, stream>>>(wf, bfin, u1bf, Gt2);
  k_conv<<<512, 256, 77824, stream>>>(xiT, Gt2, out);
}